// Round 4
// baseline (758.326 us; speedup 1.0000x reference)
//
#include <hip/hip_runtime.h>
#include <stdint.h>

// HNM discriminative loss, MI355X — R4.
// predict (4,32,512,1024) f32, target (4,512,1024) i32 -> scalar f32.
// R4: async global->LDS DMA staging (__builtin_amdgcn_global_load_lds,
// width=16) with double-buffered channel batches. DMA loads consume no
// VGPRs, so the compiler cannot serialize them (R1-R3 all collapsed to
// 1 outstanding load -> 356us regardless of source structure).

#define K_CLS 19
#define C_CH 32
#define HW_SHIFT 19            // H*W = 512*1024 = 2^19
#define HW_SIZE (1 << HW_SHIFT)
#define CHUNK 1024             // pixels per block (divides 2^19)
#define NBCH 8                 // channels per batch
#define NBATCH 4               // 32 / 8
#define EPSF 1e-12f
#define THEA_F 0.5f
#define TWO_DELTA 3.0f
#define MIN_PIX 20.0f

// ws float layout
#define OFF_SUMS 0             // 608 floats, [ch][cls] = ch*19 + s
#define OFF_CNT  608           // 19
#define OFF_SQ   627           // 19
#define OFF_POS  646           // 19
#define WS_FLOATS 665

__device__ __forceinline__ void atomAddF(float* p, float v) {
  unsafeAtomicAdd(p, v);       // native ds_add_f32 / global_atomic_add_f32
}

// One 16B-per-lane DMA: lane i moves 16B from its gptr to ldsbase + i*16.
__device__ __forceinline__ void asyncLoad16(const float* g, float* lds_uniform_base) {
  __builtin_amdgcn_global_load_lds(
      (const __attribute__((address_space(1))) void*)g,
      (__attribute__((address_space(3))) void*)lds_uniform_base,
      16, 0, 0);
}

// Stage one batch of NBCH channels (CHUNK floats each) into tile.
// Wave w stages channels 2w, 2w+1; per channel 4 DMAs of 1 KB.
__device__ __forceinline__ void stage_batch(const float* img_base, int gch0,
                                            float (*tile)[CHUNK], int t) {
  const int lane = t & 63;
  const int w = t >> 6;
#pragma unroll
  for (int j = 0; j < 2; ++j) {
    const int chl = w * 2 + j;
    const float* src = img_base + ((size_t)(gch0 + chl) << HW_SHIFT);
#pragma unroll
    for (int q = 0; q < 4; ++q) {
      asyncLoad16(src + q * 256 + lane * 4, &tile[chl][q * 256]);
    }
  }
}

// ---- Pass 1: per-class counts + feature sums ------------------------------
__global__ __launch_bounds__(256) void k_accum(
    const float* __restrict__ pred, const int* __restrict__ tgt,
    float* __restrict__ ws)
{
  __shared__ float tile[2][NBCH][CHUNK];   // 64 KB double buffer
  __shared__ float s_sums[C_CH][4][20];    // replica per quarter-wave
  __shared__ float s_cnt[4][20];
  {
    float* z = &s_sums[0][0][0];
    for (int i = threadIdx.x; i < C_CH * 4 * 20; i += 256) z[i] = 0.f;
    if (threadIdx.x < 80) (&s_cnt[0][0])[threadIdx.x] = 0.f;
  }

  const int t = threadIdx.x;
  const int rep = (t >> 4) & 3;
  const size_t P0 = (size_t)blockIdx.x * CHUNK;   // never crosses image
  const int n_idx = (int)(P0 >> HW_SHIFT);
  const int hw0 = (int)(P0 & (HW_SIZE - 1));
  const float* img = pred + (((size_t)n_idx * C_CH) << HW_SHIFT) + hw0;

  // thread owns pixels 4t..4t+3 (matches tile lane layout)
  const int4 tv = *reinterpret_cast<const int4*>(tgt + P0 + t * 4);
  int  sc[4] = {tv.x, tv.y, tv.z, tv.w};
  bool vl[4];
#pragma unroll
  for (int i = 0; i < 4; ++i) { vl[i] = (unsigned)sc[i] < K_CLS; if (!vl[i]) sc[i] = 0; }

  stage_batch(img, 0, tile[0], t);
  __syncthreads();   // drains DMA (vmcnt) + zero-init visible

#pragma unroll
  for (int i = 0; i < 4; ++i) if (vl[i]) atomAddF(&s_cnt[rep][sc[i]], 1.f);

  for (int b = 0; b < NBATCH; ++b) {
    const int buf = b & 1;
    if (b + 1 < NBATCH) stage_batch(img, (b + 1) * NBCH, tile[buf ^ 1], t);
#pragma unroll
    for (int c = 0; c < NBCH; ++c) {
      const float4 x = *reinterpret_cast<const float4*>(&tile[buf][c][4 * t]);
      const int gch = b * NBCH + c;
      const float xa[4] = {x.x, x.y, x.z, x.w};
#pragma unroll
      for (int i = 0; i < 4; ++i)
        if (vl[i]) atomAddF(&s_sums[gch][rep][sc[i]], xa[i]);
    }
    __syncthreads();  // drains next batch's DMA + guards buffer reuse
  }

  for (int i = t; i < C_CH * K_CLS; i += 256) {
    const int ch = i / K_CLS, k = i - ch * K_CLS;
    atomAddF(&ws[OFF_SUMS + i],
             s_sums[ch][0][k] + s_sums[ch][1][k] + s_sums[ch][2][k] + s_sums[ch][3][k]);
  }
  if (t < K_CLS)
    atomAddF(&ws[OFF_CNT + t], s_cnt[0][t] + s_cnt[1][t] + s_cnt[2][t] + s_cnt[3][t]);
}

// ---- Pass 2: per-pixel residuals (d^2 in registers) -> sq / pos -----------
__global__ __launch_bounds__(256) void k_var(
    const float* __restrict__ pred, const int* __restrict__ tgt,
    float* __restrict__ ws)
{
  __shared__ float tile[2][NBCH][CHUNK];   // 64 KB double buffer
  __shared__ float s_ctr[C_CH][K_CLS];
  __shared__ float s_sq[K_CLS];
  __shared__ float s_pos[K_CLS];
  for (int i = threadIdx.x; i < C_CH * K_CLS; i += 256) {
    const int k = i % K_CLS;
    (&s_ctr[0][0])[i] = ws[OFF_SUMS + i] / fmaxf(ws[OFF_CNT + k], 1.f);
  }
  if (threadIdx.x < K_CLS) { s_sq[threadIdx.x] = 0.f; s_pos[threadIdx.x] = 0.f; }

  const int t = threadIdx.x;
  const size_t P0 = (size_t)blockIdx.x * CHUNK;
  const int n_idx = (int)(P0 >> HW_SHIFT);
  const int hw0 = (int)(P0 & (HW_SIZE - 1));
  const float* img = pred + (((size_t)n_idx * C_CH) << HW_SHIFT) + hw0;

  const int4 tv = *reinterpret_cast<const int4*>(tgt + P0 + t * 4);
  int  sc[4] = {tv.x, tv.y, tv.z, tv.w};
  bool vl[4];
#pragma unroll
  for (int i = 0; i < 4; ++i) { vl[i] = (unsigned)sc[i] < K_CLS; if (!vl[i]) sc[i] = 0; }

  stage_batch(img, 0, tile[0], t);
  __syncthreads();   // drains DMA + s_ctr init visible

  float d2[4] = {0.f, 0.f, 0.f, 0.f};
  for (int b = 0; b < NBATCH; ++b) {
    const int buf = b & 1;
    if (b + 1 < NBATCH) stage_batch(img, (b + 1) * NBCH, tile[buf ^ 1], t);
#pragma unroll
    for (int c = 0; c < NBCH; ++c) {
      const float4 x = *reinterpret_cast<const float4*>(&tile[buf][c][4 * t]);
      const int gch = b * NBCH + c;
      const float xa[4] = {x.x, x.y, x.z, x.w};
#pragma unroll
      for (int i = 0; i < 4; ++i) {
        const float cc = s_ctr[gch][sc[i]];   // 19 consecutive words: conflict-free
        const float d = cc - xa[i];
        d2[i] = fmaf(d, d, d2[i]);
      }
    }
    __syncthreads();
  }

#pragma unroll
  for (int i = 0; i < 4; ++i) {
    if (vl[i]) {
      const float r = sqrtf(d2[i] + EPSF) - THEA_F;
      if (r > 0.f) { atomAddF(&s_sq[sc[i]], r * r); atomAddF(&s_pos[sc[i]], 1.f); }
    }
  }

  __syncthreads();
  if (t < K_CLS) {
    atomAddF(&ws[OFF_SQ + t], s_sq[t]);
    atomAddF(&ws[OFF_POS + t], s_pos[t]);
  }
}

// ---- Finalize: loss_var + loss_dis + 0.001*loss_reg -----------------------
__global__ __launch_bounds__(384) void k_final(
    const float* __restrict__ ws, float* __restrict__ out)
{
  __shared__ float s_ctr[C_CH * K_CLS];
  __shared__ float s_valid[K_CLS];
  __shared__ float s_red[3];
  __shared__ float s_ncls;
  const int t = threadIdx.x;
  if (t < 3) s_red[t] = 0.f;
  if (t < K_CLS) s_valid[t] = (ws[OFF_CNT + t] > MIN_PIX) ? 1.f : 0.f;
  for (int i = t; i < C_CH * K_CLS; i += 384) {
    const int k = i % K_CLS;
    s_ctr[i] = ws[OFF_SUMS + i] / fmaxf(ws[OFF_CNT + k], 1.f);
  }
  __syncthreads();
  if (t == 0) {
    float n = 0.f;
    for (int k = 0; k < K_CLS; ++k) n += s_valid[k];
    s_ncls = fmaxf(n, 1.f);
  }
  if (t < K_CLS && s_valid[t] > 0.f) {
    atomAddF(&s_red[0], ws[OFF_SQ + t] / fmaxf(ws[OFF_POS + t], 1.f));
    float nn = 0.f;
#pragma unroll
    for (int ch = 0; ch < C_CH; ++ch) {
      const float cv = s_ctr[ch * K_CLS + t];
      nn = fmaf(cv, cv, nn);
    }
    atomAddF(&s_red[2], sqrtf(nn + EPSF));
  }
  if (t < K_CLS * K_CLS) {
    const int a = t / K_CLS, b = t - (t / K_CLS) * K_CLS;
    if (a != b && s_valid[a] > 0.f && s_valid[b] > 0.f) {
      float dd = 0.f;
#pragma unroll
      for (int ch = 0; ch < C_CH; ++ch) {
        const float df = s_ctr[ch * K_CLS + a] - s_ctr[ch * K_CLS + b];
        dd = fmaf(df, df, dd);
      }
      const float dist = sqrtf(dd + EPSF);
      const float d = fmaxf(TWO_DELTA - dist, 0.f);
      if (d > 0.f) atomAddF(&s_red[1], d * d);
    }
  }
  __syncthreads();
  if (t == 0) {
    const float n = s_ncls;
    out[0] = s_red[0] / n
           + s_red[1] / fmaxf(n * (n - 1.f), 1.f)
           + 0.001f * s_red[2] / n;
  }
}

extern "C" void kernel_launch(void* const* d_in, const int* in_sizes, int n_in,
                              void* d_out, int out_size, void* d_ws, size_t ws_size,
                              hipStream_t stream) {
  const float* pred = (const float*)d_in[0];
  const int*   tgt  = (const int*)d_in[1];
  float* ws  = (float*)d_ws;
  float* out = (float*)d_out;
  const int P = in_sizes[1];            // n*h*w = 2097152
  const int nBlocks = P / CHUNK;        // 2048

  hipMemsetAsync(d_ws, 0, WS_FLOATS * sizeof(float), stream);
  k_accum<<<nBlocks, 256, 0, stream>>>(pred, tgt, ws);
  k_var  <<<nBlocks, 256, 0, stream>>>(pred, tgt, ws);
  k_final<<<1, 384, 0, stream>>>(ws, out);
}